// Round 10
// baseline (421.903 us; speedup 1.0000x reference)
//
#include <hip/hip_runtime.h>

#define B_N 131072
#define IN_N 40
#define H_N 256

typedef __bf16 bf16x8 __attribute__((ext_vector_type(8)));
typedef __bf16 bf16x4 __attribute__((ext_vector_type(4)));
typedef __bf16 bf16x2 __attribute__((ext_vector_type(2)));
typedef float f32x4 __attribute__((ext_vector_type(4)));

#define MFMA(a, b, c) __builtin_amdgcn_mfma_f32_16x16x32_bf16(a, b, c, 0, 0, 0)

// ws bf16 layout = exact LDS images for global_load_lds:
//  WSGH: [3 g][8 ks][2 hf][4 q][128 col][8 e]  <- Whh[(g*256+hf*128+col)*256 + ks*32+q*8+e]
//  WSGI: [3 g][2 ks2][2 hf][4 q][128 col][8 e] <- fused W_ih@W_proj (k=ks2*32+q*8+e, 0 for k>=40)
//  WSBI: f32 bfused[768] = b_ih + W_ih@b_proj
#define WSGH 0
#define WSGI 196608
#define WSBI 245760
#define PREP_N (245760 + 768 + B_N)

__global__ void prep(const float* __restrict__ Wp, const float* __restrict__ bp,
                     const float* __restrict__ Wih, const float* __restrict__ Whh,
                     const float* __restrict__ bih, const float* __restrict__ bhead,
                     __bf16* __restrict__ wsb, float* __restrict__ out) {
  int i = blockIdx.x * 256 + threadIdx.x;
  if (i < WSGI) {
    int e8 = i & 7, col = (i >> 3) & 127, q = (i >> 10) & 3,
        hf = (i >> 12) & 1, ks = (i >> 13) & 7, g = i >> 16;
    int gcol = hf * 128 + col, k = ks * 32 + q * 8 + e8;
    wsb[i] = (__bf16)Whh[(g * 256 + gcol) * 256 + k];
  } else if (i < WSBI) {
    int j = i - WSGI;
    int e8 = j & 7, col = (j >> 3) & 127, q = (j >> 10) & 3,
        hf = (j >> 12) & 1, ks2 = (j >> 13) & 1, g = j >> 14;
    int gcol = hf * 128 + col, k = ks2 * 32 + q * 8 + e8;
    float v = 0.f;
    if (k < IN_N)
      for (int p = 0; p < 128; ++p)
        v += Wih[(g * 256 + gcol) * 128 + p] * Wp[p * IN_N + k];
    wsb[i] = (__bf16)v;
  } else if (i < WSBI + 768) {
    int g = i - WSBI;
    float v = bih[g];
    for (int p = 0; p < 128; ++p) v += Wih[g * 128 + p] * bp[p];
    ((float*)(wsb + WSBI))[g] = v;
  } else if (i < PREP_N) {
    out[i - (WSBI + 768)] = bhead[0];  // pred init = bias; waves atomicAdd partials
  }
}

__device__ __forceinline__ void gload16(const __bf16* g, __bf16* l) {
  __builtin_amdgcn_global_load_lds(
      (const __attribute__((address_space(1))) void*)g,
      (__attribute__((address_space(3))) void*)l, 16, 0, 0);
}

// 512 blocks = 2 col-halves x 256 row-groups; 512 thr = 8 waves (2 row x 4 col).
// Block tile: 128 rows x 128 hcols x 3 gates; 4 row-tiles per block.
// B async via global_load_lds (2x24KB dbuf, barrier per K-step); A (h,x) in LDS.
__global__ __launch_bounds__(512, 1) void gru_v11(
    const float* __restrict__ x, const float* __restrict__ h0,
    const __bf16* __restrict__ wsb, const float* __restrict__ bhh,
    const float* __restrict__ Whead, float* __restrict__ out) {
  __shared__ __bf16 hs[128][264];   // 67584 B; 528B stride -> 2-way (free)
  __shared__ __bf16 xs[128][72];    // 18432 B; K padded 40->64, cols 40..71 zero
  __shared__ __bf16 Bb[2][12288];   // 49152 B; [g][q][128 col][8] per buffer

  const int tid = threadIdx.x;
  const int lane = tid & 63;
  const int w = tid >> 6;
  const int l15 = lane & 15;
  const int l4 = lane >> 4;
  const int koff = l4 * 8;
  const int rw = w >> 2, cw = w & 3;

  const int hf = blockIdx.x >> 8;        // same rows+both halves -> same XCD (bid%8)
  const int rgrp = blockIdx.x & 255;
  const size_t row0 = (size_t)rgrp * 512;

  const int colL = cw * 32 + l15;        // block-local col (ni=0)
  const int col0 = hf * 128 + colL;      // global hcol (ni=0)
  const int bofs = l4 * 1024 + colL * 8; // B ds offset: + ni*128 + g*4096

  const float* bfused = (const float*)(wsb + WSBI);
  float bR[2], bZ[2], bI[2], bH[2], wh[2];
#pragma unroll
  for (int ni = 0; ni < 2; ++ni) {
    const int c = col0 + ni * 16;
    bR[ni] = bfused[c] + bhh[c];
    bZ[ni] = bfused[256 + c] + bhh[256 + c];
    bI[ni] = bfused[512 + c];
    bH[ni] = bhh[512 + c];
    wh[ni] = Whead[c];
  }

  for (int j = tid; j < 128 * 32; j += 512) xs[j >> 5][40 + (j & 31)] = (__bf16)0.f;

  // staged tile held as bf16 (converted at issue): 16x bf16x4 + 5x bf16x2
  bf16x4 sh[16];
  bf16x2 sx[5];
  auto issueStage = [&](int t) {
    const float* hb = h0 + (row0 + (size_t)t * 128) * H_N;
#pragma unroll
    for (int k = 0; k < 16; ++k) {
      const float4 v = *reinterpret_cast<const float4*>(hb + (size_t)(tid + k * 512) * 4);
      bf16x4 u;
      u[0] = (__bf16)v.x; u[1] = (__bf16)v.y; u[2] = (__bf16)v.z; u[3] = (__bf16)v.w;
      sh[k] = u;
    }
    const float* xb = x + (row0 + (size_t)t * 128) * IN_N;
#pragma unroll
    for (int k = 0; k < 5; ++k) {
      const float2 v = *reinterpret_cast<const float2*>(xb + (size_t)(tid + k * 512) * 2);
      bf16x2 u;
      u[0] = (__bf16)v.x; u[1] = (__bf16)v.y;
      sx[k] = u;
    }
  };
  auto writeStage = [&]() {
#pragma unroll
    for (int k = 0; k < 16; ++k) {
      const int f = tid + k * 512;   // [0, 8192): full 128x256 tile
      *reinterpret_cast<bf16x4*>(&hs[f >> 6][(f & 63) * 4]) = sh[k];
    }
#pragma unroll
    for (int k = 0; k < 5; ++k) {
      const int f = tid + k * 512;   // [0, 2560) = 128 x 20 float2
      *reinterpret_cast<bf16x2*>(&xs[f / 20][(f % 20) * 2]) = sx[k];
    }
  };

  auto issueB = [&](int sn) {   // load B tile for step sn into Bb[sn&1]
    const int buf = sn & 1;
#pragma unroll
    for (int g = 0; g < 3; ++g) {
      const __bf16* gp = (sn < 2)
          ? wsb + WSGI + (size_t)((g * 2 + sn) * 2 + hf) * 4096 + w * 512 + lane * 8
          : wsb + WSGH + (size_t)((g * 8 + (sn - 2)) * 2 + hf) * 4096 + w * 512 + lane * 8;
      gload16(gp, &Bb[buf][g * 4096 + w * 512]);  // HW adds lane*16B to LDS base
    }
  };

  f32x4 aR[4][2], aZ[4][2], aI[4][2], aH[4][2];
  auto step = [&](int s) {
    const int buf = s & 1;
    bf16x8 b[3][2];
#pragma unroll
    for (int g = 0; g < 3; ++g)
#pragma unroll
      for (int ni = 0; ni < 2; ++ni)
        b[g][ni] = *reinterpret_cast<const bf16x8*>(&Bb[buf][g * 4096 + bofs + ni * 128]);
#pragma unroll
    for (int mi = 0; mi < 4; ++mi) {
      const int row = rw * 64 + mi * 16 + l15;
      const bf16x8 a = (s < 2)
          ? *reinterpret_cast<const bf16x8*>(&xs[row][s * 32 + koff])
          : *reinterpret_cast<const bf16x8*>(&hs[row][(s - 2) * 32 + koff]);
#pragma unroll
      for (int ni = 0; ni < 2; ++ni) {
        aR[mi][ni] = MFMA(a, b[0][ni], aR[mi][ni]);
        aZ[mi][ni] = MFMA(a, b[1][ni], aZ[mi][ni]);
        if (s < 2) aI[mi][ni] = MFMA(a, b[2][ni], aI[mi][ni]);
        else       aH[mi][ni] = MFMA(a, b[2][ni], aH[mi][ni]);
      }
    }
    __syncthreads();
  };

  // prologue: blocking stage of tile 0 + B(0)
  issueStage(0);
  writeStage();
  issueB(0);
  __syncthreads();

  for (int t = 0; t < 4; ++t) {
#pragma unroll
    for (int mi = 0; mi < 4; ++mi)
#pragma unroll
      for (int ni = 0; ni < 2; ++ni) {
        aR[mi][ni] = (f32x4){bR[ni], bR[ni], bR[ni], bR[ni]};
        aZ[mi][ni] = (f32x4){bZ[ni], bZ[ni], bZ[ni], bZ[ni]};
        aI[mi][ni] = (f32x4){bI[ni], bI[ni], bI[ni], bI[ni]};
        aH[mi][ni] = (f32x4){bH[ni], bH[ni], bH[ni], bH[ni]};
      }

#pragma unroll
    for (int s = 0; s < 10; ++s) {
      issueB(s == 9 ? 0 : s + 1);              // prefetch next K-step (wraps)
      if (s == 2 && t < 3) issueStage(t + 1);  // T14: issue+cvt A loads early
      step(s);
    }

    // epilogue: gates (f32), h_new store, pred partials (hv re-read from L2-hot h0)
    const size_t trow = row0 + (size_t)t * 128;
    float ps[4][4];
#pragma unroll
    for (int mi = 0; mi < 4; ++mi)
#pragma unroll
      for (int r = 0; r < 4; ++r) ps[mi][r] = 0.f;
#pragma unroll
    for (int mi = 0; mi < 4; ++mi) {
      const int rloc = rw * 64 + mi * 16 + l4 * 4;
#pragma unroll
      for (int ni = 0; ni < 2; ++ni) {
        const int c = col0 + ni * 16;
#pragma unroll
        for (int r = 0; r < 4; ++r) {
          const float rg_ = 1.f / (1.f + __expf(-aR[mi][ni][r]));
          const float zg = 1.f / (1.f + __expf(-aZ[mi][ni][r]));
          const float e2 = __expf(2.f * (aI[mi][ni][r] + rg_ * aH[mi][ni][r]));
          const float ng = (e2 - 1.f) / (e2 + 1.f);
          const float hv = h0[(trow + rloc + r) * H_N + c];
          const float hn = (1.f - zg) * ng + zg * hv;
          out[(size_t)B_N + (trow + rloc + r) * H_N + c] = hn;
          ps[mi][r] += hn * wh[ni];
        }
      }
    }
#pragma unroll
    for (int mi = 0; mi < 4; ++mi)
#pragma unroll
      for (int r = 0; r < 4; ++r) {
        float s2 = ps[mi][r];
        s2 += __shfl_xor(s2, 1);
        s2 += __shfl_xor(s2, 2);
        s2 += __shfl_xor(s2, 4);
        s2 += __shfl_xor(s2, 8);
        if (l15 == 0)
          atomicAdd(&out[trow + rw * 64 + mi * 16 + l4 * 4 + r], s2);
      }

    if (t < 3) writeStage();   // hs/xs overwrite: safe, all reads of tile t done
    __syncthreads();
  }
}

extern "C" void kernel_launch(void* const* d_in, const int* in_sizes, int n_in,
                              void* d_out, int out_size, void* d_ws, size_t ws_size,
                              hipStream_t stream) {
  const float* x     = (const float*)d_in[0];
  const float* h0    = (const float*)d_in[1];
  const float* Wp    = (const float*)d_in[2];
  const float* bp    = (const float*)d_in[3];
  const float* Wih   = (const float*)d_in[4];
  const float* Whh   = (const float*)d_in[5];
  const float* bih   = (const float*)d_in[6];
  const float* bhh   = (const float*)d_in[7];
  const float* Whead = (const float*)d_in[8];
  const float* bhead = (const float*)d_in[9];
  float* out = (float*)d_out;
  __bf16* wsb = (__bf16*)d_ws;

  prep<<<(PREP_N + 255) / 256, 256, 0, stream>>>(Wp, bp, Wih, Whh, bih, bhead, wsb, out);
  gru_v11<<<512, 512, 0, stream>>>(x, h0, wsb, bhh, Whead, out);
}

// Round 12
// 194.940 us; speedup vs baseline: 2.1643x; 2.1643x over previous
//
#include <hip/hip_runtime.h>

#define B_N 131072
#define IN_N 40
#define H_N 256

typedef __bf16 bf16x8 __attribute__((ext_vector_type(8)));
typedef float f32x4 __attribute__((ext_vector_type(4)));

#define MFMA(a, b, c) __builtin_amdgcn_mfma_f32_16x16x32_bf16(a, b, c, 0, 0, 0)

// ws bf16 layout: per-quarter contiguous weight images (LDS-identical):
//   quarter q (64 hcols): gh [3 g][8 ks][4 sub][64 col][8 e]   (49152 elems)
//                         gi [3 g][2 ks][4 sub][64 col][8 e]   (12288 elems)
//   k = ks*32 + sub*8 + e; col = block-local hcol; gi zero for k>=40
// then f32 bfused[768] = b_ih + W_ih@b_proj
#define WSQ 61440
#define WSBI (4 * WSQ)                    // 245760
#define PREP_N (245760 + 768 + B_N)

__global__ void prep(const float* __restrict__ Wp, const float* __restrict__ bp,
                     const float* __restrict__ Wih, const float* __restrict__ Whh,
                     const float* __restrict__ bih, const float* __restrict__ bhead,
                     __bf16* __restrict__ wsb, float* __restrict__ out) {
  int i = blockIdx.x * 256 + threadIdx.x;
  if (i < WSBI) {
    const int quarter = i / WSQ, r = i % WSQ;
    if (r < 49152) {  // gh
      const int g = r >> 14, ks = (r >> 11) & 7, sub = (r >> 9) & 3,
                col = (r >> 3) & 63, e = r & 7;
      const int gatecol = g * 256 + quarter * 64 + col;
      const int k = ks * 32 + sub * 8 + e;
      wsb[i] = (__bf16)Whh[(size_t)gatecol * 256 + k];
    } else {          // gi (fused)
      const int rr = r - 49152;
      const int g = rr >> 12, ks = (rr >> 11) & 1, sub = (rr >> 9) & 3,
                col = (rr >> 3) & 63, e = rr & 7;
      const int gatecol = g * 256 + quarter * 64 + col;
      const int k = ks * 32 + sub * 8 + e;
      float v = 0.f;
      if (k < IN_N)
        for (int p = 0; p < 128; ++p)
          v += Wih[(size_t)gatecol * 128 + p] * Wp[p * IN_N + k];
      wsb[i] = (__bf16)v;
    }
  } else if (i < WSBI + 768) {
    const int g = i - WSBI;
    float v = bih[g];
    for (int p = 0; p < 128; ++p) v += Wih[g * 128 + p] * bp[p];
    ((float*)(wsb + WSBI))[g] = v;
  } else if (i < PREP_N) {
    out[i - (WSBI + 768)] = bhead[0];  // pred init = bias; waves atomicAdd partials
  }
}

__device__ __forceinline__ void gload16(const __bf16* g, __bf16* l) {
  __builtin_amdgcn_global_load_lds(
      (const __attribute__((address_space(1))) void*)g,
      (__attribute__((address_space(3))) void*)l, 16, 0, 0);
}

__device__ __forceinline__ bf16x8 cvt8(float4 a, float4 b) {
  bf16x8 u;
  u[0] = (__bf16)a.x; u[1] = (__bf16)a.y; u[2] = (__bf16)a.z; u[3] = (__bf16)a.w;
  u[4] = (__bf16)b.x; u[5] = (__bf16)b.y; u[6] = (__bf16)b.z; u[7] = (__bf16)b.w;
  return u;
}

// 1024 blocks = 4 col-quarters x 256 row-groups; 512 thr = 8 waves (2rw x 4cw).
// Per block: stage its quarter's weights to LDS ONCE (120KB), then 8 tiles of
// 64 rows x 64 hcols. A-tile (h,x) single-buffered in LDS, XOR-swizzled,
// T14 split staging. Steady state: zero weight traffic, 2 barriers/tile.
__global__ __launch_bounds__(512, 1) void gru_v13(
    const float* __restrict__ x, const float* __restrict__ h0,
    const __bf16* __restrict__ wsb, const float* __restrict__ bhh,
    const float* __restrict__ Whead, float* __restrict__ out) {
  __shared__ __bf16 Wl[WSQ];      // 122880 B
  __shared__ __bf16 hsw[16384];   //  32768 B: [64 row][32 chunk^(row&7)][8]
  __shared__ __bf16 xsw[4096];    //   8192 B: [64 row][8 chunk^(row&7)][8]
                                  //  total 163840 B = 160 KiB exact

  const int tid = threadIdx.x;
  const int lane = tid & 63;
  const int w = tid >> 6;
  const int l15 = lane & 15;
  const int l4 = lane >> 4;
  const int rw = w >> 2, cw = w & 3;

  // XCD-chunked: 4 quarter-siblings + 32 consecutive row-groups per XCD
  const int lin = (blockIdx.x & 7) * 128 + (blockIdx.x >> 3);
  const int quarter = lin & 3;
  const int rgrp = lin >> 2;             // 0..255
  const size_t row0 = (size_t)rgrp * 512;

  const int colB = cw * 16 + l15;        // block-local hcol 0..63
  const int hcol = quarter * 64 + colB;

  // ---- stage weights to LDS once (120 x 1KB coalesced async copies) ----
  const __bf16* wsq = wsb + quarter * WSQ;
#pragma unroll
  for (int j = 0; j < 15; ++j) {
    const int c = (w * 15 + j) * 512;
    gload16(wsq + c + lane * 8, &Wl[c]);   // dest wave-uniform; HW adds lane*16B
  }

  // zero xsw pad chunks 5..7 (k 40..63) once; data writes never touch them
  if (tid < 192) {
    const int row = tid / 3, cz = 5 + tid % 3;
    bf16x8 z = {};
    *reinterpret_cast<bf16x8*>(&xsw[row * 64 + ((cz ^ (row & 7)) << 3)]) = z;
  }

  const float* bfused = (const float*)(wsb + WSBI);
  const float bR = bfused[hcol] + bhh[hcol];
  const float bZ = bfused[256 + hcol] + bhh[256 + hcol];
  const float bI = bfused[512 + hcol];
  const float bH = bhh[512 + hcol];
  const float wh = Whead[hcol];

  // ---- T14 split staging state (raw f32 held, cvt at write) ----
  float4 shv[8], sxv[2];
  const int xrow = tid / 5, xci = tid % 5;     // valid for tid < 320
  auto issueStage = [&](int t) {
    const float* hb = h0 + (row0 + (size_t)t * 64) * H_N;
#pragma unroll
    for (int j = 0; j < 4; ++j) {
      const int g = tid + j * 512;             // chunk 0..2047
      shv[2 * j]     = *reinterpret_cast<const float4*>(hb + g * 8);
      shv[2 * j + 1] = *reinterpret_cast<const float4*>(hb + g * 8 + 4);
    }
    if (tid < 320) {
      const float* xb = x + (row0 + (size_t)t * 64) * IN_N + xrow * IN_N + xci * 8;
      sxv[0] = *reinterpret_cast<const float4*>(xb);
      sxv[1] = *reinterpret_cast<const float4*>(xb + 4);
    }
  };
  auto writeStage = [&]() {
#pragma unroll
    for (int j = 0; j < 4; ++j) {
      const int g = tid + j * 512;
      const int row = g >> 5, ci = g & 31;
      *reinterpret_cast<bf16x8*>(&hsw[row * 256 + ((ci ^ (row & 7)) << 3)]) =
          cvt8(shv[2 * j], shv[2 * j + 1]);
    }
    if (tid < 320)
      *reinterpret_cast<bf16x8*>(&xsw[xrow * 64 + ((xci ^ (xrow & 7)) << 3)]) =
          cvt8(sxv[0], sxv[1]);
  };

  issueStage(0);
  writeStage();
  __syncthreads();   // weights (vmcnt) + A-tile + zeros all visible

  for (int t = 0; t < 8; ++t) {
    if (t < 7) issueStage(t + 1);   // global->reg overlaps compute

    f32x4 aR[2], aZ[2], aI[2], aH[2];
#pragma unroll
    for (int mi = 0; mi < 2; ++mi) {
      aR[mi] = (f32x4){bR, bR, bR, bR};
      aZ[mi] = (f32x4){bZ, bZ, bZ, bZ};
      aI[mi] = (f32x4){bI, bI, bI, bI};
      aH[mi] = (f32x4){bH, bH, bH, bH};
    }

#pragma unroll
    for (int ks = 0; ks < 10; ++ks) {
      bf16x8 b0, b1, b2;
      if (ks < 2) {
        const int base = 49152 + l4 * 512 + colB * 8;
        b0 = *reinterpret_cast<const bf16x8*>(&Wl[base + (0 * 2 + ks) * 2048]);
        b1 = *reinterpret_cast<const bf16x8*>(&Wl[base + (1 * 2 + ks) * 2048]);
        b2 = *reinterpret_cast<const bf16x8*>(&Wl[base + (2 * 2 + ks) * 2048]);
      } else {
        const int base = l4 * 512 + colB * 8;
        b0 = *reinterpret_cast<const bf16x8*>(&Wl[base + (0 * 8 + ks - 2) * 2048]);
        b1 = *reinterpret_cast<const bf16x8*>(&Wl[base + (1 * 8 + ks - 2) * 2048]);
        b2 = *reinterpret_cast<const bf16x8*>(&Wl[base + (2 * 8 + ks - 2) * 2048]);
      }
#pragma unroll
      for (int mi = 0; mi < 2; ++mi) {
        const int row = rw * 32 + mi * 16 + l15;
        bf16x8 a;
        if (ks < 2)
          a = *reinterpret_cast<const bf16x8*>(
              &xsw[row * 64 + (((ks * 4 + l4) ^ (row & 7)) << 3)]);
        else
          a = *reinterpret_cast<const bf16x8*>(
              &hsw[row * 256 + ((((ks - 2) * 4 + l4) ^ (row & 7)) << 3)]);
        aR[mi] = MFMA(a, b0, aR[mi]);
        aZ[mi] = MFMA(a, b1, aZ[mi]);
        if (ks < 2) aI[mi] = MFMA(a, b2, aI[mi]);
        else        aH[mi] = MFMA(a, b2, aH[mi]);
      }
    }

    // ---- epilogue ----
    const size_t trow = row0 + (size_t)t * 64;
    // hv column in hsw is the GLOBAL hcol (hsw holds all 256 H cols). BUG FIX
    // vs v12: chunk index must include quarter*8.
    const int chc = quarter * 8 + (colB >> 3), cofs = colB & 7;
    float ps[2][4];
#pragma unroll
    for (int mi = 0; mi < 2; ++mi) {
#pragma unroll
      for (int r = 0; r < 4; ++r) {
        const int rowl = rw * 32 + mi * 16 + l4 * 4 + r;
        const float rg = 1.f / (1.f + __expf(-aR[mi][r]));
        const float zg = 1.f / (1.f + __expf(-aZ[mi][r]));
        const float e2 = __expf(2.f * (aI[mi][r] + rg * aH[mi][r]));
        const float ng = (e2 - 1.f) / (e2 + 1.f);
        const float hv = (float)hsw[rowl * 256 + ((chc ^ (rowl & 7)) << 3) + cofs];
        const float hn = (1.f - zg) * ng + zg * hv;
        out[(size_t)B_N + (trow + rowl) * H_N + hcol] = hn;
        ps[mi][r] = hn * wh;
      }
    }
#pragma unroll
    for (int mi = 0; mi < 2; ++mi)
#pragma unroll
      for (int r = 0; r < 4; ++r) {
        float s = ps[mi][r];
        s += __shfl_xor(s, 1);
        s += __shfl_xor(s, 2);
        s += __shfl_xor(s, 4);
        s += __shfl_xor(s, 8);
        if (l15 == 0)
          atomicAdd(&out[trow + rw * 32 + mi * 16 + l4 * 4 + r], s);
      }

    __syncthreads();              // all hsw/xsw reads of tile t done
    if (t < 7) {
      writeStage();               // cvt + scatter tile t+1
      __syncthreads();            // visible to all before compute
    }
  }
}

extern "C" void kernel_launch(void* const* d_in, const int* in_sizes, int n_in,
                              void* d_out, int out_size, void* d_ws, size_t ws_size,
                              hipStream_t stream) {
  const float* x     = (const float*)d_in[0];
  const float* h0    = (const float*)d_in[1];
  const float* Wp    = (const float*)d_in[2];
  const float* bp    = (const float*)d_in[3];
  const float* Wih   = (const float*)d_in[4];
  const float* Whh   = (const float*)d_in[5];
  const float* bih   = (const float*)d_in[6];
  const float* bhh   = (const float*)d_in[7];
  const float* Whead = (const float*)d_in[8];
  const float* bhead = (const float*)d_in[9];
  float* out = (float*)d_out;
  __bf16* wsb = (__bf16*)d_ws;

  prep<<<(PREP_N + 255) / 256, 256, 0, stream>>>(Wp, bp, Wih, Whh, bih, bhead, wsb, out);
  gru_v13<<<1024, 512, 0, stream>>>(x, h0, wsb, bhh, Whead, out);
}

// Round 13
// 179.540 us; speedup vs baseline: 2.3499x; 1.0858x over previous
//
#include <hip/hip_runtime.h>

#define B_N 131072
#define IN_N 40
#define H_N 256

typedef __bf16 bf16x8 __attribute__((ext_vector_type(8)));
typedef float f32x4 __attribute__((ext_vector_type(4)));

#define MFMA(a, b, c) __builtin_amdgcn_mfma_f32_16x16x32_bf16(a, b, c, 0, 0, 0)

// ws bf16 layout: per-quarter contiguous weight images (LDS-identical):
//   quarter q (64 hcols): gh [3 g][8 ks][4 sub][64 col][8 e]   (49152 elems)
//                         gi [3 g][2 ks][4 sub][64 col][8 e]   (12288 elems)
//   k = ks*32 + sub*8 + e; col = block-local hcol; gi zero for k>=40
// then f32 bfused[768] = b_ih + W_ih@b_proj
#define WSQ 61440
#define WSBI (4 * WSQ)                    // 245760
#define PREP_N (245760 + 768 + B_N)

__global__ void prep(const float* __restrict__ Wp, const float* __restrict__ bp,
                     const float* __restrict__ Wih, const float* __restrict__ Whh,
                     const float* __restrict__ bih, const float* __restrict__ bhead,
                     __bf16* __restrict__ wsb, float* __restrict__ out) {
  int i = blockIdx.x * 256 + threadIdx.x;
  if (i < WSBI) {
    const int quarter = i / WSQ, r = i % WSQ;
    if (r < 49152) {  // gh
      const int g = r >> 14, ks = (r >> 11) & 7, sub = (r >> 9) & 3,
                col = (r >> 3) & 63, e = r & 7;
      const int gatecol = g * 256 + quarter * 64 + col;
      const int k = ks * 32 + sub * 8 + e;
      wsb[i] = (__bf16)Whh[(size_t)gatecol * 256 + k];
    } else {          // gi (fused)
      const int rr = r - 49152;
      const int g = rr >> 12, ks = (rr >> 11) & 1, sub = (rr >> 9) & 3,
                col = (rr >> 3) & 63, e = rr & 7;
      const int gatecol = g * 256 + quarter * 64 + col;
      const int k = ks * 32 + sub * 8 + e;
      float v = 0.f;
      if (k < IN_N)
        for (int p = 0; p < 128; ++p)
          v += Wih[(size_t)gatecol * 128 + p] * Wp[p * IN_N + k];
      wsb[i] = (__bf16)v;
    }
  } else if (i < WSBI + 768) {
    const int g = i - WSBI;
    float v = bih[g];
    for (int p = 0; p < 128; ++p) v += Wih[g * 128 + p] * bp[p];
    ((float*)(wsb + WSBI))[g] = v;
  } else if (i < PREP_N) {
    out[i - (WSBI + 768)] = bhead[0];  // pred init = bias; waves atomicAdd partials
  }
}

__device__ __forceinline__ void gload16(const __bf16* g, __bf16* l) {
  __builtin_amdgcn_global_load_lds(
      (const __attribute__((address_space(1))) void*)g,
      (__attribute__((address_space(3))) void*)l, 16, 0, 0);
}

__device__ __forceinline__ bf16x8 cvt8(float4 a, float4 b) {
  bf16x8 u;
  u[0] = (__bf16)a.x; u[1] = (__bf16)a.y; u[2] = (__bf16)a.z; u[3] = (__bf16)a.w;
  u[4] = (__bf16)b.x; u[5] = (__bf16)b.y; u[6] = (__bf16)b.z; u[7] = (__bf16)b.w;
  return u;
}

// 1024 blocks = 4 col-quarters x 256 row-groups; 1024 thr = 16 waves (4rw x 4cw).
// v13 structure (LDS-resident weights, 160KB exact) at 4 waves/SIMD:
// wave = 16 rows x 16 cols, 30 MFMA/tile; hv from global (epilogue off LDS
// critical path -> writeStage overlaps epilogue VALU); 2 barriers/tile.
__global__ __launch_bounds__(1024, 1) void gru_v14(
    const float* __restrict__ x, const float* __restrict__ h0,
    const __bf16* __restrict__ wsb, const float* __restrict__ bhh,
    const float* __restrict__ Whead, float* __restrict__ out) {
  __shared__ __bf16 Wl[WSQ];      // 122880 B
  __shared__ __bf16 hsw[16384];   //  32768 B: [64 row][32 chunk^(row&7)][8]
  __shared__ __bf16 xsw[4096];    //   8192 B: [64 row][8 chunk^(row&7)][8]
                                  //  total 163840 B = 160 KiB exact

  const int tid = threadIdx.x;
  const int lane = tid & 63;
  const int w = tid >> 6;              // 0..15
  const int l15 = lane & 15;
  const int l4 = lane >> 4;
  const int rw = w >> 2, cw = w & 3;   // 4 row-bands x 4 col-groups

  // XCD-chunked: 4 quarter-siblings + consecutive row-groups per XCD
  const int lin = (blockIdx.x & 7) * 128 + (blockIdx.x >> 3);
  const int quarter = lin & 3;
  const int rgrp = lin >> 2;           // 0..255
  const size_t row0 = (size_t)rgrp * 512;

  const int colB = cw * 16 + l15;      // block-local hcol 0..63
  const int hcol = quarter * 64 + colB;

  // ---- stage weights to LDS once (120 x 1KB coalesced async copies) ----
  const __bf16* wsq = wsb + quarter * WSQ;
#pragma unroll
  for (int j = 0; j < 8; ++j) {
    const int idx = j * 16 + w;        // wave-uniform
    if (idx < 120)
      gload16(wsq + idx * 512 + lane * 8, &Wl[idx * 512]);
  }

  // zero xsw pad chunks 5..7 (k 40..63) once; data writes never touch them
  if (tid < 192) {
    const int row = tid / 3, cz = 5 + tid % 3;
    bf16x8 z = {};
    *reinterpret_cast<bf16x8*>(&xsw[row * 64 + ((cz ^ (row & 7)) << 3)]) = z;
  }

  const float* bfused = (const float*)(wsb + WSBI);
  const float bR = bfused[hcol] + bhh[hcol];
  const float bZ = bfused[256 + hcol] + bhh[256 + hcol];
  const float bI = bfused[512 + hcol];
  const float bH = bhh[512 + hcol];
  const float wh = Whead[hcol];

  // ---- T14 split staging (raw f32 held, cvt at write) ----
  float4 shv[4], sxv[2];
  const int xrow = tid / 5, xci = tid % 5;   // valid for tid < 320
  auto issueStage = [&](int t) {
    const float* hb = h0 + (row0 + (size_t)t * 64) * H_N;
#pragma unroll
    for (int j = 0; j < 2; ++j) {
      const int g = tid + j * 1024;          // chunk 0..2047
      shv[2 * j]     = *reinterpret_cast<const float4*>(hb + g * 8);
      shv[2 * j + 1] = *reinterpret_cast<const float4*>(hb + g * 8 + 4);
    }
    if (tid < 320) {
      const float* xb = x + (row0 + (size_t)t * 64) * IN_N + xrow * IN_N + xci * 8;
      sxv[0] = *reinterpret_cast<const float4*>(xb);
      sxv[1] = *reinterpret_cast<const float4*>(xb + 4);
    }
  };
  auto writeStage = [&]() {
#pragma unroll
    for (int j = 0; j < 2; ++j) {
      const int g = tid + j * 1024;
      const int row = g >> 5, ci = g & 31;
      *reinterpret_cast<bf16x8*>(&hsw[row * 256 + ((ci ^ (row & 7)) << 3)]) =
          cvt8(shv[2 * j], shv[2 * j + 1]);
    }
    if (tid < 320)
      *reinterpret_cast<bf16x8*>(&xsw[xrow * 64 + ((xci ^ (xrow & 7)) << 3)]) =
          cvt8(sxv[0], sxv[1]);
  };

  issueStage(0);
  writeStage();
  __syncthreads();   // weights (vmcnt auto-drained) + A-tile + zeros visible

  for (int t = 0; t < 8; ++t) {
    if (t < 7) issueStage(t + 1);   // global->reg, hides under ks loop

    f32x4 aR = {bR, bR, bR, bR};
    f32x4 aZ = {bZ, bZ, bZ, bZ};
    f32x4 aI = {bI, bI, bI, bI};
    f32x4 aH = {bH, bH, bH, bH};

    const int arow = rw * 16 + l15;
#pragma unroll
    for (int ks = 0; ks < 10; ++ks) {
      bf16x8 b0, b1, b2, a;
      if (ks < 2) {
        const int base = 49152 + l4 * 512 + colB * 8;
        b0 = *reinterpret_cast<const bf16x8*>(&Wl[base + (0 * 2 + ks) * 2048]);
        b1 = *reinterpret_cast<const bf16x8*>(&Wl[base + (1 * 2 + ks) * 2048]);
        b2 = *reinterpret_cast<const bf16x8*>(&Wl[base + (2 * 2 + ks) * 2048]);
        a = *reinterpret_cast<const bf16x8*>(
            &xsw[arow * 64 + (((ks * 4 + l4) ^ (arow & 7)) << 3)]);
      } else {
        const int base = l4 * 512 + colB * 8;
        b0 = *reinterpret_cast<const bf16x8*>(&Wl[base + (0 * 8 + ks - 2) * 2048]);
        b1 = *reinterpret_cast<const bf16x8*>(&Wl[base + (1 * 8 + ks - 2) * 2048]);
        b2 = *reinterpret_cast<const bf16x8*>(&Wl[base + (2 * 8 + ks - 2) * 2048]);
        a = *reinterpret_cast<const bf16x8*>(
            &hsw[arow * 256 + ((((ks - 2) * 4 + l4) ^ (arow & 7)) << 3)]);
      }
      aR = MFMA(a, b0, aR);
      aZ = MFMA(a, b1, aZ);
      if (ks < 2) aI = MFMA(a, b2, aI);
      else        aH = MFMA(a, b2, aH);
    }

    __syncthreads();   // all hsw/xsw reads of tile t done (epilogue reads none)

    if (t < 7) writeStage();   // ds_writes overlap epilogue VALU below

    // ---- epilogue: gates (f32), h_new store, pred partials; hv from h0 ----
    const size_t trow = row0 + (size_t)t * 64;
    float ps[4];
#pragma unroll
    for (int r = 0; r < 4; ++r) {
      const int rowl = rw * 16 + l4 * 4 + r;
      const float rg = 1.f / (1.f + __expf(-aR[r]));
      const float zg = 1.f / (1.f + __expf(-aZ[r]));
      const float e2 = __expf(2.f * (aI[r] + rg * aH[r]));
      const float ng = (e2 - 1.f) / (e2 + 1.f);
      const float hv = h0[(trow + rowl) * H_N + hcol];   // L1/L2-hot
      const float hn = (1.f - zg) * ng + zg * hv;
      out[(size_t)B_N + (trow + rowl) * H_N + hcol] = hn;
      ps[r] = hn * wh;
    }
#pragma unroll
    for (int r = 0; r < 4; ++r) {
      float s = ps[r];
      s += __shfl_xor(s, 1);
      s += __shfl_xor(s, 2);
      s += __shfl_xor(s, 4);
      s += __shfl_xor(s, 8);
      if (l15 == 0)
        atomicAdd(&out[trow + rw * 16 + l4 * 4 + r], s);
    }

    if (t < 7) __syncthreads();   // staged writes visible before next reads
  }
}

extern "C" void kernel_launch(void* const* d_in, const int* in_sizes, int n_in,
                              void* d_out, int out_size, void* d_ws, size_t ws_size,
                              hipStream_t stream) {
  const float* x     = (const float*)d_in[0];
  const float* h0    = (const float*)d_in[1];
  const float* Wp    = (const float*)d_in[2];
  const float* bp    = (const float*)d_in[3];
  const float* Wih   = (const float*)d_in[4];
  const float* Whh   = (const float*)d_in[5];
  const float* bih   = (const float*)d_in[6];
  const float* bhh   = (const float*)d_in[7];
  const float* Whead = (const float*)d_in[8];
  const float* bhead = (const float*)d_in[9];
  float* out = (float*)d_out;
  __bf16* wsb = (__bf16*)d_ws;

  prep<<<(PREP_N + 255) / 256, 256, 0, stream>>>(Wp, bp, Wih, Whh, bih, bhead, wsb, out);
  gru_v14<<<1024, 1024, 0, stream>>>(x, h0, wsb, bhh, Whead, out);
}